// Round 1
// baseline (655.448 us; speedup 1.0000x reference)
//
#include <hip/hip_runtime.h>
#include <cstdint>

#define B_ 16
#define H_ 224
#define W_ 224
#define C_ 32
#define TS 32      // output tile (32x32), 224 = 7*32
#define RG 47      // region = TS + halo(7 top, 8 bottom) = 47
#define LDSW 49    // LDS row stride: 49 -> column stride 17 mod 32, conflict-free

// ---- order-preserving float<->uint encoding for atomic min/max ----
__device__ __forceinline__ unsigned int enc_f(float f) {
    unsigned int u = __float_as_uint(f);
    return (u & 0x80000000u) ? ~u : (u | 0x80000000u);
}
__device__ __forceinline__ float dec_f(unsigned int u) {
    u = (u & 0x80000000u) ? (u & 0x7FFFFFFFu) : ~u;
    return __uint_as_float(u);
}

// ws[0..15] = encoded per-sample min, ws[16..31] = encoded per-sample max
__global__ void init_ws(unsigned int* __restrict__ ws) {
    int t = threadIdx.x;
    if (t < 16) ws[t] = 0xFFFFFFFFu;        // +inf encoded
    else if (t < 32) ws[t] = 0u;            // -inf encoded
}

__global__ __launch_bounds__(256) void minmax_kernel(const float* __restrict__ x,
                                                     unsigned int* __restrict__ ws) {
    const int b = blockIdx.x;       // sample
    const int chunk = blockIdx.y;   // 0..63
    const int chunkElems = (H_ * W_ * C_) / 64;      // 25088, divisible by 4
    const float4* p = (const float4*)(x + (size_t)b * (H_ * W_ * C_) +
                                      (size_t)chunk * chunkElems);
    const int n4 = chunkElems / 4;                    // 6272
    float mn = 3.4e38f, mx = -3.4e38f;
    for (int i = threadIdx.x; i < n4; i += 256) {
        float4 v = p[i];
        mn = fminf(mn, fminf(fminf(v.x, v.y), fminf(v.z, v.w)));
        mx = fmaxf(mx, fmaxf(fmaxf(v.x, v.y), fmaxf(v.z, v.w)));
    }
#pragma unroll
    for (int off = 32; off > 0; off >>= 1) {
        mn = fminf(mn, __shfl_down(mn, off));
        mx = fmaxf(mx, __shfl_down(mx, off));
    }
    __shared__ float smn[4], smx[4];
    const int lane = threadIdx.x & 63, wv = threadIdx.x >> 6;
    if (lane == 0) { smn[wv] = mn; smx[wv] = mx; }
    __syncthreads();
    if (threadIdx.x == 0) {
        mn = fminf(fminf(smn[0], smn[1]), fminf(smn[2], smn[3]));
        mx = fmaxf(fmaxf(smx[0], smx[1]), fmaxf(smx[2], smx[3]));
        atomicMin(&ws[b], enc_f(mn));
        atomicMax(&ws[16 + b], enc_f(mx));
    }
}

// Main kernel: block = (b, c, 32x32 tile). SAT in LDS via wave shuffle scans.
__global__ __launch_bounds__(256) void lss_kernel(
    const float* __restrict__ x,
    const float* __restrict__ gamma, const float* __restrict__ beta,
    const float* __restrict__ mmean, const float* __restrict__ mvar,
    const unsigned int* __restrict__ ws,
    float* __restrict__ out)
{
    __shared__ float sat[RG][LDSW];   // 47*49*4 = 9212 B

    const int bid = blockIdx.x;
    const int c = bid & (C_ - 1);
    const int rem = bid >> 5;                 // b*49 + tile
    const int b = rem / 49;
    const int tile = rem - b * 49;
    const int th0 = (tile / 7) * TS;
    const int tw0 = (tile % 7) * TS;
    const int tid = threadIdx.x;

    const float mn = dec_f(ws[b]);
    const float mx = dec_f(ws[16 + b]);
    const float inv = 1.0f / (mx - mn + 1e-7f);
    const size_t sbase = (size_t)b * (H_ * W_ * C_) + c;

    // Load scaled 47x47 region (zeros outside image = TF SAME zero padding)
    for (int idx = tid; idx < RG * RG; idx += 256) {
        const int i = idx / RG;
        const int j = idx - i * RG;
        const int gh = th0 - 7 + i;
        const int gw = tw0 - 7 + j;
        float v = 0.0f;
        if (gh >= 0 && gh < H_ && gw >= 0 && gw < W_)
            v = (x[sbase + ((size_t)(gh * W_ + gw)) * C_] - mn) * inv;
        sat[i][j] = v;
    }
    __syncthreads();

    const int lane = tid & 63, wv = tid >> 6;
    // Row-wise inclusive scans (one wave per row, round-robin)
    for (int r = wv; r < RG; r += 4) {
        float v = (lane < RG) ? sat[r][lane] : 0.0f;
#pragma unroll
        for (int off = 1; off < 64; off <<= 1) {
            float n = __shfl_up(v, off);
            if (lane >= off) v += n;
        }
        if (lane < RG) sat[r][lane] = v;
    }
    __syncthreads();
    // Column-wise inclusive scans -> full 2D SAT
    for (int col = wv; col < RG; col += 4) {
        float v = (lane < RG) ? sat[lane][col] : 0.0f;
#pragma unroll
        for (int off = 1; off < 64; off <<= 1) {
            float n = __shfl_up(v, off);
            if (lane >= off) v += n;
        }
        if (lane < RG) sat[lane][col] = v;
    }
    __syncthreads();

    const float sc = gamma[c] * rsqrtf(mvar[c] + 1e-3f);
    const float mm0 = mmean[c];
    const float bt = beta[c];

    // 1024 outputs, 4 per thread. Windows (TF SAME, kernel r):
    // lo = r/2 - 1, hi = r/2  =>  r=2:(0,1) r=4:(1,2) r=8:(3,4) r=16:(7,8)
#pragma unroll
    for (int k = 0; k < 4; ++k) {
        const int idx = k * 256 + tid;
        const int hl = idx >> 5;          // 0..31
        const int wl = idx & 31;          // 0..31
        const int lh = hl + 7;            // region-local row
        const int lw = wl + 7;            // region-local col
        const int lo_[4] = {0, 1, 3, 7};
        const int hi_[4] = {1, 2, 4, 8};
        float l[4];
#pragma unroll
        for (int s = 0; s < 4; ++s) {
            const int r0 = lh - lo_[s] - 1;
            const int r1 = lh + hi_[s];
            const int c0 = lw - lo_[s] - 1;
            const int c1 = lw + hi_[s];
            const float Sll = (r0 >= 0 && c0 >= 0) ? sat[r0][c0] : 0.0f;
            const float Slh = (r0 >= 0) ? sat[r0][c1] : 0.0f;
            const float Shl = (c0 >= 0) ? sat[r1][c0] : 0.0f;
            const float Shh = sat[r1][c1];
            float box = (Shh - Slh) - (Shl - Sll);
            box = fmaxf(box, 0.0f);                 // guard fp cancellation
            l[s] = __log2f(box + 1e-7f);
        }
        // alpha = OLS slope of ln(m) vs ln(scale); ln2 factors cancel:
        const float alpha = 0.2f * (1.5f * (l[3] - l[0]) + 0.5f * (l[2] - l[1]));
        const float o = (alpha - mm0) * sc + bt;
        out[sbase + ((size_t)((th0 + hl) * W_ + (tw0 + wl))) * C_] = o;
    }
}

extern "C" void kernel_launch(void* const* d_in, const int* in_sizes, int n_in,
                              void* d_out, int out_size, void* d_ws, size_t ws_size,
                              hipStream_t stream) {
    const float* x     = (const float*)d_in[0];
    const float* gamma = (const float*)d_in[1];
    const float* beta  = (const float*)d_in[2];
    const float* mmean = (const float*)d_in[3];
    const float* mvar  = (const float*)d_in[4];
    float* out = (float*)d_out;
    unsigned int* ws = (unsigned int*)d_ws;

    hipLaunchKernelGGL(init_ws, dim3(1), dim3(64), 0, stream, ws);
    hipLaunchKernelGGL(minmax_kernel, dim3(16, 64), dim3(256), 0, stream, x, ws);
    hipLaunchKernelGGL(lss_kernel, dim3(B_ * 49 * C_), dim3(256), 0, stream,
                       x, gamma, beta, mmean, mvar, ws, out);
}

// Round 2
// 586.351 us; speedup vs baseline: 1.1178x; 1.1178x over previous
//
#include <hip/hip_runtime.h>
#include <cstdint>

#define B_ 16
#define H_ 224
#define W_ 224
#define C_ 32
#define TS 32      // output tile (32x32), 224 = 7*32
#define RG 47      // region = TS + halo(7 top, 8 bottom) = 47
#define LDSW 49    // LDS row stride: 49 -> column stride 17 mod 32, conflict-free

// ---- order-preserving float<->uint encoding for atomic min/max ----
__device__ __forceinline__ unsigned int enc_f(float f) {
    unsigned int u = __float_as_uint(f);
    return (u & 0x80000000u) ? ~u : (u | 0x80000000u);
}
__device__ __forceinline__ float dec_f(unsigned int u) {
    u = (u & 0x80000000u) ? (u & 0x7FFFFFFFu) : ~u;
    return __uint_as_float(u);
}

// ws[0..15] = encoded per-sample min, ws[16..31] = encoded per-sample max
__global__ void init_ws(unsigned int* __restrict__ ws) {
    int t = threadIdx.x;
    if (t < 16) ws[t] = 0xFFFFFFFFu;        // +inf encoded
    else if (t < 32) ws[t] = 0u;            // -inf encoded
}

__global__ __launch_bounds__(256) void minmax_kernel(const float* __restrict__ x,
                                                     unsigned int* __restrict__ ws) {
    const int b = blockIdx.x;       // sample
    const int chunk = blockIdx.y;   // 0..63
    const int chunkElems = (H_ * W_ * C_) / 64;      // 25088, divisible by 4
    const float4* p = (const float4*)(x + (size_t)b * (H_ * W_ * C_) +
                                      (size_t)chunk * chunkElems);
    const int n4 = chunkElems / 4;                    // 6272
    float mn = 3.4e38f, mx = -3.4e38f;
    for (int i = threadIdx.x; i < n4; i += 256) {
        float4 v = p[i];
        mn = fminf(mn, fminf(fminf(v.x, v.y), fminf(v.z, v.w)));
        mx = fmaxf(mx, fmaxf(fmaxf(v.x, v.y), fmaxf(v.z, v.w)));
    }
#pragma unroll
    for (int off = 32; off > 0; off >>= 1) {
        mn = fminf(mn, __shfl_down(mn, off));
        mx = fmaxf(mx, __shfl_down(mx, off));
    }
    __shared__ float smn[4], smx[4];
    const int lane = threadIdx.x & 63, wv = threadIdx.x >> 6;
    if (lane == 0) { smn[wv] = mn; smx[wv] = mx; }
    __syncthreads();
    if (threadIdx.x == 0) {
        mn = fminf(fminf(smn[0], smn[1]), fminf(smn[2], smn[3]));
        mx = fmaxf(fmaxf(smx[0], smx[1]), fmaxf(smx[2], smx[3]));
        atomicMin(&ws[b], enc_f(mn));
        atomicMax(&ws[16 + b], enc_f(mx));
    }
}

// Main kernel: one block per (b, 32x32 tile), ALL 32 channels handled inside
// the block via an 8-iteration loop over channel-groups of 4 (float4 I/O).
// This keeps every 64B/128B cache line produced by a single block on a single
// XCD so L2 write-combines partial stores into full lines (fixes the 10x
// write amplification seen in round 1).
__global__ __launch_bounds__(512) void lss_kernel(
    const float* __restrict__ x,
    const float* __restrict__ gamma, const float* __restrict__ beta,
    const float* __restrict__ mmean, const float* __restrict__ mvar,
    const unsigned int* __restrict__ ws,
    float* __restrict__ out)
{
    __shared__ float sat[4][RG][LDSW];   // 4 channel planes, 36,848 B

    const int bid = blockIdx.x;
    const int b = bid / 49;
    const int tile = bid - b * 49;
    const int th0 = (tile / 7) * TS;
    const int tw0 = (tile % 7) * TS;
    const int tid = threadIdx.x;
    const int lane = tid & 63, wv = tid >> 6;   // 8 waves

    const float mn = dec_f(ws[b]);
    const float mx = dec_f(ws[16 + b]);
    const float inv = 1.0f / (mx - mn + 1e-7f);

    const float* xb = x + (size_t)b * (H_ * W_ * C_);
    float* ob = out + (size_t)b * (H_ * W_ * C_);

    const int lo_[4] = {0, 1, 3, 7};
    const int hi_[4] = {1, 2, 4, 8};

    for (int cg = 0; cg < 8; ++cg) {
        // ---- load scaled 47x47 region, 4 channels at once ----
        for (int idx = tid; idx < RG * RG; idx += 512) {
            const int i = idx / RG;
            const int j = idx - i * RG;
            const int gh = th0 - 7 + i;
            const int gw = tw0 - 7 + j;
            float4 v = make_float4(0.f, 0.f, 0.f, 0.f);
            if (gh >= 0 && gh < H_ && gw >= 0 && gw < W_) {
                const float4 t = *(const float4*)(xb + ((size_t)(gh * W_ + gw)) * C_ + cg * 4);
                v.x = (t.x - mn) * inv;
                v.y = (t.y - mn) * inv;
                v.z = (t.z - mn) * inv;
                v.w = (t.w - mn) * inv;
            }
            sat[0][i][j] = v.x;
            sat[1][i][j] = v.y;
            sat[2][i][j] = v.z;
            sat[3][i][j] = v.w;
        }
        __syncthreads();

        // ---- row-wise inclusive scans (188 = 4 planes x 47 rows) ----
        for (int sid = wv; sid < 4 * RG; sid += 8) {
            const int p = sid & 3;
            const int r = sid >> 2;
            float v = (lane < RG) ? sat[p][r][lane] : 0.0f;
#pragma unroll
            for (int off = 1; off < 64; off <<= 1) {
                float n = __shfl_up(v, off);
                v = (lane >= off) ? v + n : v;
            }
            if (lane < RG) sat[p][r][lane] = v;
        }
        __syncthreads();

        // ---- column-wise inclusive scans -> full 2D SAT per plane ----
        for (int sid = wv; sid < 4 * RG; sid += 8) {
            const int p = sid & 3;
            const int cc = sid >> 2;
            float v = (lane < RG) ? sat[p][lane][cc] : 0.0f;
#pragma unroll
            for (int off = 1; off < 64; off <<= 1) {
                float n = __shfl_up(v, off);
                v = (lane >= off) ? v + n : v;
            }
            if (lane < RG) sat[p][lane][cc] = v;
        }
        __syncthreads();

        // ---- BN constants for this channel group ----
        const float4 g  = *(const float4*)(gamma + cg * 4);
        const float4 be = *(const float4*)(beta  + cg * 4);
        const float4 mm = *(const float4*)(mmean + cg * 4);
        const float4 mv = *(const float4*)(mvar  + cg * 4);
        float scv[4] = { g.x * rsqrtf(mv.x + 1e-3f), g.y * rsqrtf(mv.y + 1e-3f),
                         g.z * rsqrtf(mv.z + 1e-3f), g.w * rsqrtf(mv.w + 1e-3f) };
        float mmv[4] = { mm.x, mm.y, mm.z, mm.w };
        float btv[4] = { be.x, be.y, be.z, be.w };

        // ---- compute: 1024 outputs, 2 per thread, 4 channels each ----
#pragma unroll
        for (int k = 0; k < 2; ++k) {
            const int idx = k * 512 + tid;
            const int hl = idx >> 5;          // 0..31
            const int wl = idx & 31;          // 0..31
            const int lh = hl + 7;            // region-local row
            const int lw = wl + 7;            // region-local col
            float o[4];
#pragma unroll
            for (int p = 0; p < 4; ++p) {
                float l[4];
#pragma unroll
                for (int s = 0; s < 4; ++s) {
                    const int r0 = lh - lo_[s] - 1;
                    const int r1 = lh + hi_[s];
                    const int c0 = lw - lo_[s] - 1;
                    const int c1 = lw + hi_[s];
                    const float Sll = (r0 >= 0 && c0 >= 0) ? sat[p][r0][c0] : 0.0f;
                    const float Slh = (r0 >= 0) ? sat[p][r0][c1] : 0.0f;
                    const float Shl = (c0 >= 0) ? sat[p][r1][c0] : 0.0f;
                    const float Shh = sat[p][r1][c1];
                    float box = (Shh - Slh) - (Shl - Sll);
                    box = fmaxf(box, 0.0f);
                    l[s] = __log2f(box + 1e-7f);
                }
                const float alpha = 0.2f * (1.5f * (l[3] - l[0]) + 0.5f * (l[2] - l[1]));
                o[p] = (alpha - mmv[p]) * scv[p] + btv[p];
            }
            float4 ov = make_float4(o[0], o[1], o[2], o[3]);
            *(float4*)(ob + ((size_t)((th0 + hl) * W_ + (tw0 + wl))) * C_ + cg * 4) = ov;
        }
        __syncthreads();   // before next cg overwrites sat
    }
}

extern "C" void kernel_launch(void* const* d_in, const int* in_sizes, int n_in,
                              void* d_out, int out_size, void* d_ws, size_t ws_size,
                              hipStream_t stream) {
    const float* x     = (const float*)d_in[0];
    const float* gamma = (const float*)d_in[1];
    const float* beta  = (const float*)d_in[2];
    const float* mmean = (const float*)d_in[3];
    const float* mvar  = (const float*)d_in[4];
    float* out = (float*)d_out;
    unsigned int* ws = (unsigned int*)d_ws;

    hipLaunchKernelGGL(init_ws, dim3(1), dim3(64), 0, stream, ws);
    hipLaunchKernelGGL(minmax_kernel, dim3(16, 64), dim3(256), 0, stream, x, ws);
    hipLaunchKernelGGL(lss_kernel, dim3(B_ * 49), dim3(512), 0, stream,
                       x, gamma, beta, mmean, mvar, ws, out);
}

// Round 3
// 408.007 us; speedup vs baseline: 1.6065x; 1.4371x over previous
//
#include <hip/hip_runtime.h>
#include <cstdint>

#define B_ 16
#define H_ 224
#define W_ 224
#define C_ 32
#define TS 32      // output tile (32x32), 224 = 7*32
#define RG 47      // region = TS + halo(7 top, 8 bottom)
#define LW 48      // LDS row width (cols 0..47; exclusive-prefix needs col 47)
#define APSTR (RG*LW)   // 2256 words per plane in buffer A
#define BROWS 46
#define BPSTR (BROWS*LW) // 2208 words per plane in buffer B

// ---- order-preserving float<->uint encoding for atomic min/max ----
__device__ __forceinline__ unsigned int enc_f(float f) {
    unsigned int u = __float_as_uint(f);
    return (u & 0x80000000u) ? ~u : (u | 0x80000000u);
}
__device__ __forceinline__ float dec_f(unsigned int u) {
    u = (u & 0x80000000u) ? (u & 0x7FFFFFFFu) : ~u;
    return __uint_as_float(u);
}

__global__ void init_ws(unsigned int* __restrict__ ws) {
    int t = threadIdx.x;
    if (t < 16) ws[t] = 0xFFFFFFFFu;
    else if (t < 32) ws[t] = 0u;
}

__global__ __launch_bounds__(256) void minmax_kernel(const float* __restrict__ x,
                                                     unsigned int* __restrict__ ws) {
    const int b = blockIdx.x;
    const int chunk = blockIdx.y;
    const int chunkElems = (H_ * W_ * C_) / 64;
    const float4* p = (const float4*)(x + (size_t)b * (H_ * W_ * C_) +
                                      (size_t)chunk * chunkElems);
    const int n4 = chunkElems / 4;
    float mn = 3.4e38f, mx = -3.4e38f;
    for (int i = threadIdx.x; i < n4; i += 256) {
        float4 v = p[i];
        mn = fminf(mn, fminf(fminf(v.x, v.y), fminf(v.z, v.w)));
        mx = fmaxf(mx, fmaxf(fmaxf(v.x, v.y), fmaxf(v.z, v.w)));
    }
#pragma unroll
    for (int off = 32; off > 0; off >>= 1) {
        mn = fminf(mn, __shfl_down(mn, off));
        mx = fmaxf(mx, __shfl_down(mx, off));
    }
    __shared__ float smn[4], smx[4];
    const int lane = threadIdx.x & 63, wv = threadIdx.x >> 6;
    if (lane == 0) { smn[wv] = mn; smx[wv] = mx; }
    __syncthreads();
    if (threadIdx.x == 0) {
        mn = fminf(fminf(smn[0], smn[1]), fminf(smn[2], smn[3]));
        mx = fmaxf(fmaxf(smx[0], smx[1]), fmaxf(smx[2], smx[3]));
        atomicMin(&ws[b], enc_f(mn));
        atomicMax(&ws[16 + b], enc_f(mx));
    }
}

// Vectorized doubling level: dst[p][r][c] = src[p][r][c] + src[p][r+sh][c]
__device__ __forceinline__ void vlevel(float* __restrict__ dst, const float* __restrict__ src,
                                       int rows, int sh, int dstr, int sstr, int tid) {
    const int perPlane = rows * (LW / 4);       // float4 jobs per plane
    const int nj = 4 * perPlane;
    for (int jb = tid; jb < nj; jb += 512) {
        const int p = jb / perPlane;
        const int rem = jb - p * perPlane;
        const int r = rem / (LW / 4);
        const int ch = rem - r * (LW / 4);
        const float* s0 = src + p * sstr + r * LW + ch * 4;
        const float* s1 = s0 + sh * LW;
        float4 a = *(const float4*)s0;
        float4 b = *(const float4*)s1;
        float4 o; o.x = a.x + b.x; o.y = a.y + b.y; o.z = a.z + b.z; o.w = a.w + b.w;
        *(float4*)(dst + p * dstr + r * LW + ch * 4) = o;
    }
}

// lss: block = (tile, split). split s covers channels s*16..s*16+15 via 4 cg
// iterations of 4 channels (float4). Block swizzle keeps both splits of a
// tile on the same XCD, 8 dispatches apart, so L2 merges half-line writes.
__global__ __launch_bounds__(512) void lss_kernel(
    const float* __restrict__ x,
    const float* __restrict__ gamma, const float* __restrict__ beta,
    const float* __restrict__ mmean, const float* __restrict__ mvar,
    const unsigned int* __restrict__ ws,
    float* __restrict__ out)
{
    __shared__ float Abuf[4][RG][LW];      // 36,096 B : raw -> excl-prefix H -> VH4 -> VH16
    __shared__ float Bbuf[4][BROWS][LW];   // 35,328 B : VH2 -> VH8

    const int bi = blockIdx.x;
    const int grp = bi >> 4, wi = bi & 15;
    const int s = (wi >> 3) & 1;
    const int tile = grp * 8 + (wi & 7);
    const int b = tile / 49;
    const int t2 = tile - b * 49;
    const int th0 = (t2 / 7) * TS;
    const int tw0 = (t2 % 7) * TS;
    const int tid = threadIdx.x;
    const int lane = tid & 63, wv = tid >> 6;  // 8 waves
    const int il = lane & 15, gl = lane >> 4;  // 16-lane scan groups

    const float mn = dec_f(ws[b]);
    const float mx = dec_f(ws[16 + b]);
    const float inv = 1.0f / (mx - mn + 1e-7f);

    const float* xb = x + (size_t)b * (H_ * W_ * C_);
    float* ob = out + (size_t)b * (H_ * W_ * C_);
    float* A = &Abuf[0][0][0];
    float* Bp = &Bbuf[0][0][0];

    for (int cc = 0; cc < 4; ++cc) {
        const int ch0 = s * 16 + cc * 4;
        float acc[2][4];
#pragma unroll
        for (int k = 0; k < 2; ++k)
#pragma unroll
            for (int p = 0; p < 4; ++p) acc[k][p] = 0.0f;

        __syncthreads();   // protect A/B from previous iteration's consumers

        // ---- P0: stage scaled raw into A (cols 0..46) ----
        for (int idx = tid; idx < RG * RG; idx += 512) {
            const int i = idx / RG;
            const int j = idx - i * RG;
            const int gh = th0 - 7 + i;
            const int gw = tw0 - 7 + j;
            float4 v = make_float4(0.f, 0.f, 0.f, 0.f);
            if (gh >= 0 && gh < H_ && gw >= 0 && gw < W_) {
                const float4 t = *(const float4*)(xb + ((size_t)(gh * W_ + gw)) * C_ + ch0);
                v.x = (t.x - mn) * inv; v.y = (t.y - mn) * inv;
                v.z = (t.z - mn) * inv; v.w = (t.w - mn) * inv;
            }
            const int base = i * LW + j;
            A[0 * APSTR + base] = v.x;
            A[1 * APSTR + base] = v.y;
            A[2 * APSTR + base] = v.z;
            A[3 * APSTR + base] = v.w;
        }
        __syncthreads();

        // ---- P1: row-wise EXCLUSIVE prefix, in place in A ----
        // 188 row-jobs (4 planes x 47 rows), 4 per wave-op via 16-lane groups.
#pragma unroll
        for (int it = 0; it < 6; ++it) {
            const int op = wv + 8 * it;
            if (op < 47) {
                const int j = 4 * op + gl;       // 0..187
                const int p = j / RG;
                const int r = j - p * RG;
                float* row = A + p * APSTR + r * LW;
                float4 v = make_float4(0.f, 0.f, 0.f, 0.f);
                if (il < 12) v = *(const float4*)(row + 4 * il);
                const float t1 = v.x;
                const float t2s = t1 + v.y;
                const float t3 = t2s + v.z;
                const float t4 = t3 + v.w;
                float sv = t4;
#pragma unroll
                for (int off = 1; off < 16; off <<= 1) {
                    float n = __shfl_up(sv, off, 16);
                    if (il >= off) sv += n;
                }
                const float carry = sv - t4;     // exclusive carry for this lane
                if (il < 12) {
                    float4 o; o.x = carry; o.y = carry + t1; o.z = carry + t2s; o.w = carry + t3;
                    *(float4*)(row + 4 * il) = o;
                }
            }
        }
        __syncthreads();

        // ---- P2: VH2 = H[r] + H[r+1]  (A -> B, rows 0..45) ----
        vlevel(Bp, A, 46, 1, BPSTR, APSTR, tid);
        __syncthreads();

        // ---- P3: consume scale 2 (B) + VH4 = VH2[r]+VH2[r+2] (B -> A, rows 0..43)
        {
#pragma unroll
            for (int k = 0; k < 2; ++k) {
                const int idx = k * 512 + tid;
                const int hl = idx >> 5, wl = idx & 31;
                const int row = hl + 7;                 // o - lo2, lo2=0
                const int c0 = wl + 7, c1 = wl + 9;     // hi2=1
#pragma unroll
                for (int p = 0; p < 4; ++p) {
                    const float* rp = Bp + p * BPSTR + row * LW;
                    float bx = rp[c1] - rp[c0];
                    acc[k][p] += -0.3f * __log2f(fmaxf(bx, 0.0f) + 1e-7f);
                }
            }
            vlevel(A, Bp, 44, 2, APSTR, BPSTR, tid);
        }
        __syncthreads();

        // ---- P4: consume scale 4 (A) + VH8 = VH4[r]+VH4[r+4] (A -> B, rows 0..39)
        {
#pragma unroll
            for (int k = 0; k < 2; ++k) {
                const int idx = k * 512 + tid;
                const int hl = idx >> 5, wl = idx & 31;
                const int row = hl + 6;                 // o - lo4, lo4=1
                const int c0 = wl + 6, c1 = wl + 10;    // hi4=2
#pragma unroll
                for (int p = 0; p < 4; ++p) {
                    const float* rp = A + p * APSTR + row * LW;
                    float bx = rp[c1] - rp[c0];
                    acc[k][p] += -0.1f * __log2f(fmaxf(bx, 0.0f) + 1e-7f);
                }
            }
            vlevel(Bp, A, 40, 4, BPSTR, APSTR, tid);
        }
        __syncthreads();

        // ---- P5: consume scale 8 (B) + VH16 = VH8[r]+VH8[r+8] (B -> A, rows 0..31)
        {
#pragma unroll
            for (int k = 0; k < 2; ++k) {
                const int idx = k * 512 + tid;
                const int hl = idx >> 5, wl = idx & 31;
                const int row = hl + 4;                 // o - lo8, lo8=3
                const int c0 = wl + 4, c1 = wl + 12;    // hi8=4
#pragma unroll
                for (int p = 0; p < 4; ++p) {
                    const float* rp = Bp + p * BPSTR + row * LW;
                    float bx = rp[c1] - rp[c0];
                    acc[k][p] += 0.1f * __log2f(fmaxf(bx, 0.0f) + 1e-7f);
                }
            }
            vlevel(A, Bp, 32, 8, APSTR, BPSTR, tid);
        }
        __syncthreads();

        // ---- P6: consume scale 16 (A), finalize, store ----
        const float4 g  = *(const float4*)(gamma + ch0);
        const float4 be = *(const float4*)(beta  + ch0);
        const float4 mm = *(const float4*)(mmean + ch0);
        const float4 mv = *(const float4*)(mvar  + ch0);
        const float scv[4] = { g.x * rsqrtf(mv.x + 1e-3f), g.y * rsqrtf(mv.y + 1e-3f),
                               g.z * rsqrtf(mv.z + 1e-3f), g.w * rsqrtf(mv.w + 1e-3f) };
        const float mmv[4] = { mm.x, mm.y, mm.z, mm.w };
        const float btv[4] = { be.x, be.y, be.z, be.w };
#pragma unroll
        for (int k = 0; k < 2; ++k) {
            const int idx = k * 512 + tid;
            const int hl = idx >> 5, wl = idx & 31;
            const int row = hl;                         // o - lo16, lo16=7
            const int c0 = wl, c1 = wl + 16;            // hi16=8
            float o[4];
#pragma unroll
            for (int p = 0; p < 4; ++p) {
                const float* rp = A + p * APSTR + row * LW;
                float bx = rp[c1] - rp[c0];
                const float alpha = acc[k][p] + 0.3f * __log2f(fmaxf(bx, 0.0f) + 1e-7f);
                o[p] = (alpha - mmv[p]) * scv[p] + btv[p];
            }
            float4 ov = make_float4(o[0], o[1], o[2], o[3]);
            *(float4*)(ob + ((size_t)((th0 + hl) * W_ + (tw0 + wl))) * C_ + ch0) = ov;
        }
    }
}

extern "C" void kernel_launch(void* const* d_in, const int* in_sizes, int n_in,
                              void* d_out, int out_size, void* d_ws, size_t ws_size,
                              hipStream_t stream) {
    const float* x     = (const float*)d_in[0];
    const float* gamma = (const float*)d_in[1];
    const float* beta  = (const float*)d_in[2];
    const float* mmean = (const float*)d_in[3];
    const float* mvar  = (const float*)d_in[4];
    float* out = (float*)d_out;
    unsigned int* ws = (unsigned int*)d_ws;

    hipLaunchKernelGGL(init_ws, dim3(1), dim3(64), 0, stream, ws);
    hipLaunchKernelGGL(minmax_kernel, dim3(16, 64), dim3(256), 0, stream, x, ws);
    hipLaunchKernelGGL(lss_kernel, dim3(98 * 16), dim3(512), 0, stream,
                       x, gamma, beta, mmean, mvar, ws, out);
}